// Round 1
// baseline (254.137 us; speedup 1.0000x reference)
//
#include <hip/hip_runtime.h>
#include <stdint.h>

typedef __attribute__((ext_vector_type(8))) short short8;
typedef __attribute__((ext_vector_type(4))) float f32x4;

__device__ __forceinline__ short f2bf(float f){
  uint32_t u = __builtin_bit_cast(uint32_t, f);
  uint32_t r = (u + 0x7fffu + ((u >> 16) & 1u)) >> 16;   // RTNE
  return (short)r;
}

__device__ __forceinline__ void gload16(const void* g, void* l){
  __builtin_amdgcn_global_load_lds((const __attribute__((address_space(1))) void*)g,
                                   (__attribute__((address_space(3))) void*)l, 16, 0, 0);
}

// ---------------- fp32 -> bf16 conversion of q,k,v,Wq,Wk,Wv,Wo ----------------
__global__ __launch_bounds__(256) void cvt_all(
    const float* __restrict__ q, const float* __restrict__ k, const float* __restrict__ v,
    const float* __restrict__ wq, const float* __restrict__ wk, const float* __restrict__ wv,
    const float* __restrict__ wo, short* __restrict__ dst){
  const size_t SQ = 4096ull*1024ull, NW = 1024ull*1024ull;
  size_t e = (size_t)(blockIdx.x*256u + threadIdx.x)*8ull;
  const float* src; size_t rel;
  if (e < 3*SQ){ size_t which = e / SQ; src = which==0?q:(which==1?k:v); rel = e - which*SQ; }
  else { size_t e2 = e - 3*SQ; size_t which = e2 / NW;
         src = which==0?wq:(which==1?wk:(which==2?wv:wo)); rel = e2 - which*NW; }
  float4 a = *(const float4*)(src + rel);
  float4 b = *(const float4*)(src + rel + 4);
  short8 r;
  r[0]=f2bf(a.x); r[1]=f2bf(a.y); r[2]=f2bf(a.z); r[3]=f2bf(a.w);
  r[4]=f2bf(b.x); r[5]=f2bf(b.y); r[6]=f2bf(b.z); r[7]=f2bf(b.w);
  *(short8*)(dst + e) = r;
}

// ---------------- NT GEMM: C[M=4096,N=1024] = A[M,K]·Bw[N,K]^T + bias ----------------
// MODE 0: bf16 out, head-scatter into [B,H,S,D]. MODE 1: f32 out, linear [M,N].
template<int MODE>
__global__ __launch_bounds__(256) void gemm_nt(const short* __restrict__ A, const short* __restrict__ Bw,
    const float* __restrict__ bias, void* __restrict__ Cout){
  const int K = 1024;
  int i = blockIdx.y*gridDim.x + blockIdx.x;   // 256 wgs
  int L = (i & 7)*32 + (i >> 3);               // XCD-contiguous chunks (256 % 8 == 0)
  int by = L >> 3, bx = L & 7;
  int m0 = by*128, n0 = bx*128;
  __shared__ short Al[128*32];
  __shared__ short Bl[128*32];
  int tid = threadIdx.x;
  int w = tid >> 6, lane = tid & 63, lr = lane & 15, lg = lane >> 4;
  int wr = w >> 1, wc = w & 1;
  f32x4 acc[4][4] = {};
  int sr = tid >> 2, sc = (tid & 3)*8;
  const short* Ag = A  + (size_t)(m0 + sr)*K + sc;
  const short* Bg = Bw + (size_t)(n0 + sr)*K + sc;
  char* Alb = (char*)Al + tid*16;
  char* Blb = (char*)Bl + tid*16;
  for (int k0 = 0; k0 < K; k0 += 32){
    gload16(Ag + k0,               Alb);
    gload16(Ag + k0 + 64*(size_t)K, Alb + 4096);
    gload16(Bg + k0,               Blb);
    gload16(Bg + k0 + 64*(size_t)K, Blb + 4096);
    __syncthreads();
    short8 av[4], bv[4];
#pragma unroll
    for (int mi=0; mi<4; ++mi) av[mi] = *(const short8*)&Al[(wr*64 + mi*16 + lr)*32 + lg*8];
#pragma unroll
    for (int ni=0; ni<4; ++ni) bv[ni] = *(const short8*)&Bl[(wc*64 + ni*16 + lr)*32 + lg*8];
#pragma unroll
    for (int mi=0; mi<4; ++mi)
#pragma unroll
      for (int ni=0; ni<4; ++ni)
        acc[mi][ni] = __builtin_amdgcn_mfma_f32_16x16x32_bf16(av[mi], bv[ni], acc[mi][ni], 0, 0, 0);
    __syncthreads();
  }
#pragma unroll
  for (int ni=0; ni<4; ++ni){
    int col = n0 + wc*64 + ni*16 + lr;
    float bb = bias[col];
#pragma unroll
    for (int mi=0; mi<4; ++mi){
#pragma unroll
      for (int i2=0; i2<4; ++i2){
        int row = m0 + wr*64 + mi*16 + lg*4 + i2;
        float val = acc[mi][ni][i2] + bb;
        if (MODE == 0){
          int b = row >> 11, s = row & 2047, h = col >> 6, d = col & 63;
          ((short*)Cout)[(((size_t)(b*16 + h))*2048 + s)*64 + d] = f2bf(val);
        } else {
          ((float*)Cout)[(size_t)row*1024 + col] = val;
        }
      }
    }
  }
}

// ---------------- flash attention: [B,H,S,D] bf16 -> AO [B,S,H*D] bf16 ----------------
__global__ __launch_bounds__(256) void attn_fwd(const short* __restrict__ Qh, const short* __restrict__ Kh,
    const short* __restrict__ Vh, short* __restrict__ AO){
  const int D = 64, S = 2048;
  int i = blockIdx.y*gridDim.x + blockIdx.x;   // 512 wgs
  int L = (i & 7)*64 + (i >> 3);               // 4 bh (2MB K+V) per XCD chunk
  int bh = L >> 4, qt = L & 15;
  __shared__ short Kl[64*64];        // source-swizzled (chunk ^= row&7)
  __shared__ short Vt[64*70];        // V^T, padded stride 70
  __shared__ short Pl[4*32*72];      // per-wave P, padded stride 72
  int tid = threadIdx.x, w = tid >> 6, lane = tid & 63, lr = lane & 15, lg = lane >> 4;
  const short* Qb = Qh + (size_t)bh*S*D;
  const short* Kb = Kh + (size_t)bh*S*D;
  const short* Vb = Vh + (size_t)bh*S*D;
  int q0 = qt*128 + w*32;
  short8 aq[2][2];
#pragma unroll
  for (int m=0; m<2; ++m)
#pragma unroll
    for (int h=0; h<2; ++h)
      aq[m][h] = *(const short8*)&Qb[(size_t)(q0 + m*16 + lr)*64 + h*32 + lg*8];
  f32x4 o[2][4] = {};
  float mrow[2][4], lsum[2][4];
#pragma unroll
  for (int m=0; m<2; ++m)
#pragma unroll
    for (int j=0; j<4; ++j){ mrow[m][j] = -1e30f; lsum[m][j] = 0.f; }
  const float Csc = 0.18033688011112042f;   // log2(e)/8
  short* Pw = &Pl[w*32*72];
  int koff0 = tid*16;         int kr0 = koff0 >> 7, kc0 = (koff0 >> 4) & 7;
  int koff1 = koff0 + 4096;   int kr1 = koff1 >> 7, kc1 = (koff1 >> 4) & 7;

  for (int kt = 0; kt < 32; ++kt){
    int k0 = kt*64;
    // K tile: global_load_lds, swizzle applied on the global source chunk
    gload16(Kb + (size_t)(k0 + kr0)*64 + ((kc0 ^ (kr0 & 7))*8), (char*)Kl + koff0);
    gload16(Kb + (size_t)(k0 + kr1)*64 + ((kc1 ^ (kr1 & 7))*8), (char*)Kl + koff1);
    // V tile: reg-stage + transpose into Vt[d][k]
#pragma unroll
    for (int s2=0; s2<2; ++s2){
      int e = tid*8 + s2*2048;
      int vr = e >> 6, d0 = e & 63;
      short8 vv = *(const short8*)&Vb[(size_t)(k0 + vr)*64 + d0];
#pragma unroll
      for (int j=0; j<8; ++j) Vt[(d0 + j)*70 + vr] = vv[j];
    }
    __syncthreads();
    // S = Q·K^T  (raw scores; scale folded into exp2)
    f32x4 sc_[2][4];
#pragma unroll
    for (int nf=0; nf<4; ++nf){
      int row = nf*16 + lr;
      short8 b0 = *(const short8*)&Kl[row*64 + ((lg    ) ^ (lr & 7))*8];
      short8 b1 = *(const short8*)&Kl[row*64 + ((lg + 4) ^ (lr & 7))*8];
#pragma unroll
      for (int m=0; m<2; ++m){
        f32x4 z = {};
        z = __builtin_amdgcn_mfma_f32_16x16x32_bf16(aq[m][0], b0, z, 0, 0, 0);
        sc_[m][nf] = __builtin_amdgcn_mfma_f32_16x16x32_bf16(aq[m][1], b1, z, 0, 0, 0);
      }
    }
    // online softmax (rows live in 16-lane groups)
    float pr[2][4][4];
#pragma unroll
    for (int m=0; m<2; ++m){
#pragma unroll
      for (int i2=0; i2<4; ++i2){
        float tm = fmaxf(fmaxf(sc_[m][0][i2], sc_[m][1][i2]), fmaxf(sc_[m][2][i2], sc_[m][3][i2]));
        tm = fmaxf(tm, __shfl_xor(tm, 1));
        tm = fmaxf(tm, __shfl_xor(tm, 2));
        tm = fmaxf(tm, __shfl_xor(tm, 4));
        tm = fmaxf(tm, __shfl_xor(tm, 8));
        float mo = mrow[m][i2];
        float mn = fmaxf(mo, tm);
        float rs = exp2f((mo - mn)*Csc);
        mrow[m][i2] = mn;
        float ps = 0.f;
#pragma unroll
        for (int nf=0; nf<4; ++nf){
          float p = exp2f((sc_[m][nf][i2] - mn)*Csc);
          pr[m][nf][i2] = p; ps += p;
        }
        ps += __shfl_xor(ps, 1); ps += __shfl_xor(ps, 2);
        ps += __shfl_xor(ps, 4); ps += __shfl_xor(ps, 8);
        lsum[m][i2] = lsum[m][i2]*rs + ps;
#pragma unroll
        for (int df=0; df<4; ++df) o[m][df][i2] *= rs;
      }
    }
    // P -> per-wave LDS (D-layout -> A-layout round trip)
#pragma unroll
    for (int m=0; m<2; ++m)
#pragma unroll
      for (int nf=0; nf<4; ++nf)
#pragma unroll
        for (int i2=0; i2<4; ++i2)
          Pw[(m*16 + lg*4 + i2)*72 + nf*16 + lr] = f2bf(pr[m][nf][i2]);
    // O += P·V
    short8 pa[2][2];
#pragma unroll
    for (int m=0; m<2; ++m)
#pragma unroll
      for (int h=0; h<2; ++h)
        pa[m][h] = *(const short8*)&Pw[(m*16 + lr)*72 + h*32 + lg*8];
#pragma unroll
    for (int df=0; df<4; ++df){
      short8 v0 = *(const short8*)&Vt[(df*16 + lr)*70 + lg*8];
      short8 v1 = *(const short8*)&Vt[(df*16 + lr)*70 + 32 + lg*8];
#pragma unroll
      for (int m=0; m<2; ++m){
        o[m][df] = __builtin_amdgcn_mfma_f32_16x16x32_bf16(pa[m][0], v0, o[m][df], 0, 0, 0);
        o[m][df] = __builtin_amdgcn_mfma_f32_16x16x32_bf16(pa[m][1], v1, o[m][df], 0, 0, 0);
      }
    }
    __syncthreads();
  }
  // epilogue: normalize, write AO[b][s][h*64+d]
  int b = bh >> 4, hh = bh & 15;
#pragma unroll
  for (int m=0; m<2; ++m)
#pragma unroll
    for (int df=0; df<4; ++df)
#pragma unroll
      for (int i2=0; i2<4; ++i2){
        int row = q0 + m*16 + lg*4 + i2;
        int col = df*16 + lr;
        float val = o[m][df][i2] / lsum[m][i2];
        AO[((size_t)(b*2048 + row))*1024 + hh*64 + col] = f2bf(val);
      }
}

extern "C" void kernel_launch(void* const* d_in, const int* in_sizes, int n_in,
                              void* d_out, int out_size, void* d_ws, size_t ws_size,
                              hipStream_t stream){
  const float* q  = (const float*)d_in[0];
  const float* k  = (const float*)d_in[1];
  const float* v  = (const float*)d_in[2];
  const float* Wq = (const float*)d_in[3];
  const float* bq = (const float*)d_in[4];
  const float* Wk = (const float*)d_in[5];
  const float* bk = (const float*)d_in[6];
  const float* Wv = (const float*)d_in[7];
  const float* bv = (const float*)d_in[8];
  const float* Wo = (const float*)d_in[9];
  const float* bo = (const float*)d_in[10];

  const size_t SQ = 4096ull*1024ull, NW = 1024ull*1024ull;
  short* ws  = (short*)d_ws;
  short* qb  = ws;                    // bf16 q      [4096,1024]
  short* kb  = ws + SQ;
  short* vb  = ws + 2*SQ;
  short* Wqb = ws + 3*SQ;             // bf16 weights [1024,1024]
  short* Wkb = Wqb + NW;
  short* Wvb = Wkb + NW;
  short* Wob = Wvb + NW;
  short* Qh  = Wob + NW;              // [B,H,S,D] bf16
  short* Kh  = Qh + SQ;
  short* Vh  = Kh + SQ;
  short* AO  = qb;                    // reuse q buffer for attention output

  cvt_all<<<8192, 256, 0, stream>>>(q, k, v, Wq, Wk, Wv, Wo, ws);
  gemm_nt<0><<<dim3(8, 32), 256, 0, stream>>>(qb, Wqb, bq, Qh);
  gemm_nt<0><<<dim3(8, 32), 256, 0, stream>>>(kb, Wkb, bk, Kh);
  gemm_nt<0><<<dim3(8, 32), 256, 0, stream>>>(vb, Wvb, bv, Vh);
  attn_fwd<<<dim3(16, 32), 256, 0, stream>>>(Qh, Kh, Vh, AO);
  gemm_nt<1><<<dim3(8, 32), 256, 0, stream>>>(AO, Wob, bo, d_out);
}

// Round 2
// 172.003 us; speedup vs baseline: 1.4775x; 1.4775x over previous
//
#include <hip/hip_runtime.h>
#include <stdint.h>

typedef __attribute__((ext_vector_type(8))) short short8;
typedef __attribute__((ext_vector_type(4))) float f32x4;

#if __has_builtin(__builtin_amdgcn_exp2f)
#define EXP2(x) __builtin_amdgcn_exp2f(x)
#else
#define EXP2(x) exp2f(x)
#endif

__device__ __forceinline__ short f2bf(float f){
  uint32_t u = __builtin_bit_cast(uint32_t, f);
  uint32_t r = (u + 0x7fffu + ((u >> 16) & 1u)) >> 16;   // RTNE
  return (short)r;
}
__device__ __forceinline__ uint32_t pk2(float a, float b){
  return ((uint32_t)(uint16_t)f2bf(b) << 16) | (uint16_t)f2bf(a);
}
__device__ __forceinline__ void gload16(const void* g, void* l){
  __builtin_amdgcn_global_load_lds((const __attribute__((address_space(1))) void*)g,
                                   (__attribute__((address_space(3))) void*)l, 16, 0, 0);
}

// ---------------- fp32 -> bf16 conversion of q,k,v,Wq,Wk,Wv,Wo ----------------
__global__ __launch_bounds__(256) void cvt_all(
    const float* __restrict__ q, const float* __restrict__ k, const float* __restrict__ v,
    const float* __restrict__ wq, const float* __restrict__ wk, const float* __restrict__ wv,
    const float* __restrict__ wo, short* __restrict__ dst){
  const size_t SQ = 4096ull*1024ull, NW = 1024ull*1024ull;
  size_t e = (size_t)(blockIdx.x*256u + threadIdx.x)*8ull;
  const float* src; size_t rel;
  if (e < 3*SQ){ size_t which = e / SQ; src = which==0?q:(which==1?k:v); rel = e - which*SQ; }
  else { size_t e2 = e - 3*SQ; size_t which = e2 / NW;
         src = which==0?wq:(which==1?wk:(which==2?wv:wo)); rel = e2 - which*NW; }
  float4 a = *(const float4*)(src + rel);
  float4 b = *(const float4*)(src + rel + 4);
  short8 r;
  r[0]=f2bf(a.x); r[1]=f2bf(a.y); r[2]=f2bf(a.z); r[3]=f2bf(a.w);
  r[4]=f2bf(b.x); r[5]=f2bf(b.y); r[6]=f2bf(b.z); r[7]=f2bf(b.w);
  *(short8*)(dst + e) = r;
}

// ---------------- NT GEMM: C[M=4096,N=1024] = A[M,K]·Bw[N,K]^T + bias ----------------
// 128x64 tile, 512 blocks (2/CU). MODE 0: bf16 head-scatter out. MODE 1: f32 linear out.
template<int MODE>
__global__ __launch_bounds__(256) void gemm_nt(const short* __restrict__ A, const short* __restrict__ Bw,
    const float* __restrict__ bias, void* __restrict__ Cout){
  const int K = 1024;
  int i = blockIdx.y*gridDim.x + blockIdx.x;   // 512 wgs
  int L = (i & 7)*64 + (i >> 3);               // XCD-contiguous chunks
  int by = L >> 4, bx = L & 15;
  int m0 = by*128, n0 = bx*64;
  __shared__ short Al[128*32];
  __shared__ short Bl[64*32];
  int tid = threadIdx.x;
  int w = tid >> 6, lane = tid & 63, lr = lane & 15, lg = lane >> 4;
  int wr = w >> 1, wc = w & 1;
  f32x4 acc[4][2] = {};
  int sr = tid >> 2, sc = (tid & 3)*8;
  const short* Ag = A  + (size_t)(m0 + sr)*K + sc;
  const short* Bg = Bw + (size_t)(n0 + (sr & 63))*K + sc;
  char* Alb = (char*)Al + tid*16;
  char* Blb = (char*)Bl + tid*16;
  for (int k0 = 0; k0 < K; k0 += 32){
    gload16(Ag + k0,                Alb);
    gload16(Ag + k0 + 64*(size_t)K, Alb + 4096);
    if (tid < 256) gload16(Bg + k0, Blb);
    __syncthreads();
    short8 av[4], bv[2];
#pragma unroll
    for (int mi=0; mi<4; ++mi) av[mi] = *(const short8*)&Al[(wr*64 + mi*16 + lr)*32 + lg*8];
#pragma unroll
    for (int ni=0; ni<2; ++ni) bv[ni] = *(const short8*)&Bl[(wc*32 + ni*16 + lr)*32 + lg*8];
#pragma unroll
    for (int mi=0; mi<4; ++mi)
#pragma unroll
      for (int ni=0; ni<2; ++ni)
        acc[mi][ni] = __builtin_amdgcn_mfma_f32_16x16x32_bf16(av[mi], bv[ni], acc[mi][ni], 0, 0, 0);
    __syncthreads();
  }
#pragma unroll
  for (int ni=0; ni<2; ++ni){
    int col = n0 + wc*32 + ni*16 + lr;
    float bb = bias[col];
#pragma unroll
    for (int mi=0; mi<4; ++mi){
#pragma unroll
      for (int i2=0; i2<4; ++i2){
        int row = m0 + wr*64 + mi*16 + lg*4 + i2;
        float val = acc[mi][ni][i2] + bb;
        if (MODE == 0){
          int b = row >> 11, s = row & 2047, h = col >> 6, d = col & 63;
          ((short*)Cout)[(((size_t)(b*16 + h))*2048 + s)*64 + d] = f2bf(val);
        } else {
          ((float*)Cout)[(size_t)row*1024 + col] = val;
        }
      }
    }
  }
}

// ---------------- flash attention (swapped QK^T, fixed-max softmax) ----------------
__global__ __launch_bounds__(256) void attn_fwd(const short* __restrict__ Qh, const short* __restrict__ Kh,
    const short* __restrict__ Vh, short* __restrict__ AO){
  const int S = 2048;
  int i = blockIdx.y*gridDim.x + blockIdx.x;   // 512 wgs
  int L = (i & 7)*64 + (i >> 3);
  int bh = L >> 4, qt = L & 15;
  __shared__ short Kl[2][64*64];     // double-buffered K, source-swizzled (block ^= row&7)
  __shared__ short Vt[2][64*72];     // double-buffered V^T[d][k], col-block swizzle by (row>>3)&7
  __shared__ short Pl[4][32*72];     // per-wave P[q][k]
  int tid = threadIdx.x, w = tid >> 6, lane = tid & 63, lr = lane & 15, lg = lane >> 4;
  const short* Qb = Qh + (size_t)bh*S*64;
  const short* Kb = Kh + (size_t)bh*S*64;
  const short* Vb = Vh + (size_t)bh*S*64;
  int q0 = qt*128 + w*32;
  short8 aq[2][2];
#pragma unroll
  for (int m=0; m<2; ++m)
#pragma unroll
    for (int h=0; h<2; ++h)
      aq[m][h] = *(const short8*)&Qb[(size_t)(q0 + m*16 + lr)*64 + h*32 + lg*8];
  f32x4 o[2][4] = {};
  float lsum[2] = {0.f, 0.f};
  const float C = 0.18033688011112042f;   // log2(e)/8
  short* Pw = &Pl[w][0];
  // K staging addressing
  int koff = tid*16;                       // byte offset in 8192B K buffer
  int kr = tid >> 3, kc = tid & 7;
  int ksrc = kr*64 + ((kc ^ (kr & 7)) << 3);   // elem offset in K tile (first 32 rows)
  // V staging addressing
  int vr = w*8 + (lane >> 3);              // k-row (s2 adds +32)
  int d0 = (lane & 7)*8;                   // d-block start; swizzle col' = k ^ d0
  // ---- prologue: stage tile 0 ----
  gload16(Kb + ksrc,        (char*)&Kl[0][0] + koff);
  gload16(Kb + ksrc + 2048, (char*)&Kl[0][0] + koff + 4096);
  {
    short8 v0 = *(const short8*)&Vb[(size_t)vr*64 + d0];
    short8 v1 = *(const short8*)&Vb[(size_t)(vr + 32)*64 + d0];
    int c0 = vr ^ d0, c1 = (vr + 32) ^ d0;
#pragma unroll
    for (int j=0; j<8; ++j) Vt[0][(d0 + j)*72 + c0] = v0[j];
#pragma unroll
    for (int j=0; j<8; ++j) Vt[0][(d0 + j)*72 + c1] = v1[j];
  }
  __syncthreads();

  for (int t = 0; t < 32; ++t){
    int buf = t & 1, nbuf = buf ^ 1;
    short8 nv0, nv1;
    bool pre = (t + 1 < 32);
    if (pre){
      const short* Kt = Kb + (size_t)(t + 1)*4096;
      gload16(Kt + ksrc,        (char*)&Kl[nbuf][0] + koff);
      gload16(Kt + ksrc + 2048, (char*)&Kl[nbuf][0] + koff + 4096);
      nv0 = *(const short8*)&Vb[(size_t)((t + 1)*64 + vr)*64 + d0];
      nv1 = *(const short8*)&Vb[(size_t)((t + 1)*64 + vr + 32)*64 + d0];
    }
    // QK^T (swapped: S^T = K·Q^T) + softmax(fixed max) + packed P write
    const short* Kbuf = &Kl[buf][0];
#pragma unroll
    for (int nf=0; nf<4; ++nf){
      int row = nf*16 + lr;
      short8 ak0 = *(const short8*)&Kbuf[row*64 + ((lg ^ (lr & 7)) << 3)];
      short8 ak1 = *(const short8*)&Kbuf[row*64 + (((lg + 4) ^ (lr & 7)) << 3)];
#pragma unroll
      for (int m=0; m<2; ++m){
        f32x4 z = {};
        z = __builtin_amdgcn_mfma_f32_16x16x32_bf16(ak0, aq[m][0], z, 0, 0, 0);
        z = __builtin_amdgcn_mfma_f32_16x16x32_bf16(ak1, aq[m][1], z, 0, 0, 0);
        float p0 = EXP2(z[0]*C), p1 = EXP2(z[1]*C);
        float p2 = EXP2(z[2]*C), p3 = EXP2(z[3]*C);
        lsum[m] += (p0 + p1) + (p2 + p3);
        uint2 pw; pw.x = pk2(p0, p1); pw.y = pk2(p2, p3);
        *(uint2*)&Pw[(m*16 + lr)*72 + nf*16 + (lg << 2)] = pw;
      }
    }
    // PV: O += P·V
    short8 pa[2][2];
#pragma unroll
    for (int m=0; m<2; ++m)
#pragma unroll
      for (int c=0; c<2; ++c)
        pa[m][c] = *(const short8*)&Pw[(m*16 + lr)*72 + c*32 + (lg << 3)];
    const short* Vbuf = &Vt[buf][0];
#pragma unroll
    for (int df=0; df<4; ++df){
      int h = (df*2 + (lr >> 3)) & 7;
      int rowv = (df*16 + lr)*72;
      short8 vb0 = *(const short8*)&Vbuf[rowv + ((lg ^ h) << 3)];
      short8 vb1 = *(const short8*)&Vbuf[rowv + (((lg + 4) ^ h) << 3)];
#pragma unroll
      for (int m=0; m<2; ++m){
        o[m][df] = __builtin_amdgcn_mfma_f32_16x16x32_bf16(pa[m][0], vb0, o[m][df], 0, 0, 0);
        o[m][df] = __builtin_amdgcn_mfma_f32_16x16x32_bf16(pa[m][1], vb1, o[m][df], 0, 0, 0);
      }
    }
    if (pre){
      short* Vn = &Vt[nbuf][0];
      int c0 = vr ^ d0, c1 = (vr + 32) ^ d0;
#pragma unroll
      for (int j=0; j<8; ++j) Vn[(d0 + j)*72 + c0] = nv0[j];
#pragma unroll
      for (int j=0; j<8; ++j) Vn[(d0 + j)*72 + c1] = nv1[j];
    }
    __syncthreads();
  }
  // epilogue: reduce lsum across lane groups, normalize, write AO[b][s][h*64+d]
  lsum[0] += __shfl_xor(lsum[0], 16); lsum[0] += __shfl_xor(lsum[0], 32);
  lsum[1] += __shfl_xor(lsum[1], 16); lsum[1] += __shfl_xor(lsum[1], 32);
  int b = bh >> 4, hh = bh & 15;
#pragma unroll
  for (int m=0; m<2; ++m){
    float rinv[4];
#pragma unroll
    for (int i2=0; i2<4; ++i2) rinv[i2] = 1.0f / __shfl(lsum[m], (lg << 2) + i2);
#pragma unroll
    for (int df=0; df<4; ++df)
#pragma unroll
      for (int i2=0; i2<4; ++i2){
        int row = q0 + m*16 + lg*4 + i2;
        int col = df*16 + lr;
        AO[((size_t)(b*2048 + row))*1024 + hh*64 + col] = f2bf(o[m][df][i2] * rinv[i2]);
      }
  }
}

extern "C" void kernel_launch(void* const* d_in, const int* in_sizes, int n_in,
                              void* d_out, int out_size, void* d_ws, size_t ws_size,
                              hipStream_t stream){
  const float* q  = (const float*)d_in[0];
  const float* k  = (const float*)d_in[1];
  const float* v  = (const float*)d_in[2];
  const float* Wq = (const float*)d_in[3];
  const float* bq = (const float*)d_in[4];
  const float* Wk = (const float*)d_in[5];
  const float* bk = (const float*)d_in[6];
  const float* Wv = (const float*)d_in[7];
  const float* bv = (const float*)d_in[8];
  const float* Wo = (const float*)d_in[9];
  const float* bo = (const float*)d_in[10];

  const size_t SQ = 4096ull*1024ull, NW = 1024ull*1024ull;
  short* ws  = (short*)d_ws;
  short* qb  = ws;                    // bf16 q      [4096,1024]
  short* kb  = ws + SQ;
  short* vb  = ws + 2*SQ;
  short* Wqb = ws + 3*SQ;             // bf16 weights [1024,1024]
  short* Wkb = Wqb + NW;
  short* Wvb = Wkb + NW;
  short* Wob = Wvb + NW;
  short* Qh  = Wob + NW;              // [B,H,S,D] bf16
  short* Kh  = Qh + SQ;
  short* Vh  = Kh + SQ;
  short* AO  = qb;                    // reuse q buffer for attention output

  cvt_all<<<8192, 256, 0, stream>>>(q, k, v, Wq, Wk, Wv, Wo, ws);
  gemm_nt<0><<<dim3(16, 32), 256, 0, stream>>>(qb, Wqb, bq, Qh);
  gemm_nt<0><<<dim3(16, 32), 256, 0, stream>>>(kb, Wkb, bk, Kh);
  gemm_nt<0><<<dim3(16, 32), 256, 0, stream>>>(vb, Wvb, bv, Vh);
  attn_fwd<<<dim3(16, 32), 256, 0, stream>>>(Qh, Kh, Vh, AO);
  gemm_nt<1><<<dim3(16, 32), 256, 0, stream>>>(AO, Wob, bo, d_out);
}